// Round 2
// baseline (5524.561 us; speedup 1.0000x reference)
//
#include <hip/hip_runtime.h>
#include <hip/hip_cooperative_groups.h>
#include <math.h>

#define B_ 256
#define T_ 576
#define FT_ 24
#define M_ 32
#define H_ 256
#define E_ 512
#define KX_ 544   // E + M
#define G_ 1024   // 4H
#define ND_ 2048  // 2*4H
#define EPS_ 1e-6f
#define GRID_ 256
#define NTH_ 65536   // GRID_ * 256

typedef __attribute__((ext_vector_type(8))) short bf8;   // 8 bf16 in 4 VGPRs
typedef __attribute__((ext_vector_type(4))) float f4;

__device__ __forceinline__ float bf2f(unsigned short s) {
    union { unsigned u; float f; } c; c.u = ((unsigned)s) << 16; return c.f;
}
__device__ __forceinline__ short f2bf(float f) {
    union { float f; unsigned u; } c; c.f = f;
    unsigned r = c.u + 0x7fffu + ((c.u >> 16) & 1u);   // round-to-nearest-even
    return (short)(r >> 16);
}
__device__ __forceinline__ float sigm(float x) { return 1.f / (1.f + expf(-x)); }

struct Prm {
    const float *enc, *fhist, *ff, *hidden, *cell;
    const float *aW1, *ab1, *aW2, *ab2;
    const float *Wih, *Whh, *bih, *bhh;
    const float *fW1, *fb1, *fW2, *fb2;
    float* out;
    float *alpha, *cbuf, *logit, *ctx, *gates;
    short *xb, *s1, *W1b, *W2b, *Wihb, *Whhb, *fW1b, *encb;
};

struct SMem {
    union {
        struct { short As[64][40]; short Bs[64][40]; } g;   // 10240 B
        struct { float wt[T_]; float red[4]; } c;           // 2320 B
    } u;
    float ypart[64];
};

// 64x64 output tile GEMM: acc += A[64xK] * Wt[64xK]^T ; A,Wt pre-offset to tile base.
__device__ __forceinline__ void gemm64(const short* __restrict__ A, int lda,
                                       const short* __restrict__ Wt, int ldw, int K,
                                       short (*As)[40], short (*Bs)[40], int tid,
                                       f4 acc[2][2]) {
    int lane = tid & 63, w = tid >> 6;
    int wm = (w & 1) * 32, wn = (w >> 1) * 32;
    int r = tid >> 2, cg = (tid & 3) * 8;
    int fr = lane & 15, fk = (lane >> 4) * 8;
    int nch = K / 32;
    int4 pa = *(const int4*)(A + r * lda + cg);
    int4 pb = *(const int4*)(Wt + r * ldw + cg);
    for (int kc = 0; kc < nch; kc++) {
        *(int4*)&As[r][cg] = pa;
        *(int4*)&Bs[r][cg] = pb;
        __syncthreads();
        if (kc + 1 < nch) {
            int ko = (kc + 1) * 32 + cg;
            pa = *(const int4*)(A + r * lda + ko);
            pb = *(const int4*)(Wt + r * ldw + ko);
        }
        bf8 a0 = *(const bf8*)&As[wm + fr][fk];
        bf8 a1 = *(const bf8*)&As[wm + 16 + fr][fk];
        bf8 b0 = *(const bf8*)&Bs[wn + fr][fk];
        bf8 b1 = *(const bf8*)&Bs[wn + 16 + fr][fk];
        acc[0][0] = __builtin_amdgcn_mfma_f32_16x16x32_bf16(a0, b0, acc[0][0], 0, 0, 0);
        acc[0][1] = __builtin_amdgcn_mfma_f32_16x16x32_bf16(a0, b1, acc[0][1], 0, 0, 0);
        acc[1][0] = __builtin_amdgcn_mfma_f32_16x16x32_bf16(a1, b0, acc[1][0], 0, 0, 0);
        acc[1][1] = __builtin_amdgcn_mfma_f32_16x16x32_bf16(a1, b1, acc[1][1], 0, 0, 0);
        __syncthreads();
    }
}

// fused fc1(relu) + fc2 dot, one 64x64 z-tile per block; atomicAdd into out[row*FT+step]
__device__ __forceinline__ void fc_tile(const Prm& p, SMem& sm, int fb, int step, int tid) {
    int m0 = (fb >> 2) * 64, n0 = (fb & 3) * 64;
    f4 acc[2][2] = {};
    gemm64(p.xb + m0 * KX_, KX_, p.fW1b + n0 * E_, E_, E_, sm.u.g.As, sm.u.g.Bs, tid, acc);
    if (tid < 64) sm.ypart[tid] = 0.f;
    __syncthreads();
    int lane = tid & 63, w = tid >> 6;
    int wm = (w & 1) * 32, wn = (w >> 1) * 32;
    int colb = n0 + wn + (lane & 15);
    int rloc = wm + (lane >> 4) * 4;
    #pragma unroll
    for (int im = 0; im < 2; im++)
        #pragma unroll
        for (int q = 0; q < 4; q++) {
            float s = 0.f;
            #pragma unroll
            for (int in = 0; in < 2; in++) {
                int col = colb + in * 16;
                s += fmaxf(acc[im][in][q] + p.fb1[col], 0.f) * p.fW2[col];
            }
            #pragma unroll
            for (int off = 1; off < 16; off <<= 1) s += __shfl_xor(s, off);
            if ((lane & 15) == 0) atomicAdd(&sm.ypart[rloc + im * 16 + q], s);
        }
    __syncthreads();
    if (tid < 64) atomicAdd(&p.out[(m0 + tid) * FT_ + step], sm.ypart[tid]);
}

__global__ __launch_bounds__(256) void k_all(Prm p) {
    cooperative_groups::grid_group grid = cooperative_groups::this_grid();
    __shared__ SMem sm;
    const int blk = blockIdx.x, tid = threadIdx.x;

    // ================= setup stage =================
    {
        int gt = blk * 256 + tid;
        auto cast = [&](const float* s, short* d, int n4) {
            for (int i = gt; i < n4; i += NTH_) {
                float4 v = ((const float4*)s)[i];
                short4 o; o.x = f2bf(v.x); o.y = f2bf(v.y); o.z = f2bf(v.z); o.w = f2bf(v.w);
                ((short4*)d)[i] = o;
            }
        };
        cast(p.aW1, p.W1b, T_ * KX_ / 4);
        cast(p.aW2, p.W2b, T_ * T_ / 4);
        cast(p.Wih, p.Wihb, ND_ * KX_ / 4);
        cast(p.Whh, p.Whhb, ND_ * H_ / 4);
        cast(p.fW1, p.fW1b, H_ * E_ / 4);
        cast(p.enc, p.encb, B_ * T_ * E_ / 4);
        // alpha: raw dp = 1/sum_p dist  (softmax finalized by block 36 in stage A of t=0)
        for (int idx = gt; idx < B_ * 24; idx += NTH_) {
            int b = idx / 24, tt = idx % 24;
            const float* fp = p.ff + (b * FT_ + tt) * M_;
            float fv[M_];
            #pragma unroll
            for (int m = 0; m < M_; m++) fv[m] = fp[m];
            float dist = 0.f;
            for (int pp = 0; pp < 24; pp++) {
                const float* hp = p.fhist + (b * T_ + pp * 24 + tt) * M_;
                float s = 0.f;
                #pragma unroll
                for (int m = 0; m < M_; m++) { float d = fv[m] - hp[m] + EPS_; s += d * d; }
                dist += sqrtf(s);
            }
            p.alpha[idx] = 1.f / dist;
        }
        // init x0 = [h0|h1|ff0] bf16, c fp32
        for (int i = gt; i < 2 * B_ * H_; i += NTH_) {
            int d = i >> 16, b = (i >> 8) & 255, j = i & 255;
            p.xb[b * KX_ + d * H_ + j] = f2bf(p.hidden[i]);
            p.cbuf[i] = p.cell[i];
            if (d == 0 && j < M_) p.xb[b * KX_ + E_ + j] = f2bf(p.ff[(b * FT_ + 0) * M_ + j]);
        }
    }
    grid.sync();

    for (int t = 0; t < FT_; t++) {
        // ===== stage A: attn1 (blocks 0..35) || fc of step t-1 (blocks 36..51) =====
        if (blk < 36) {
            int n0 = (blk % 9) * 64, m0 = (blk / 9) * 64;
            f4 acc[2][2] = {};
            gemm64(p.xb + m0 * KX_, KX_, p.W1b + n0 * KX_, KX_, KX_,
                   sm.u.g.As, sm.u.g.Bs, tid, acc);
            int lane = tid & 63, w = tid >> 6;
            int wm = (w & 1) * 32, wn = (w >> 1) * 32;
            int colb = n0 + wn + (lane & 15);
            int rowb = m0 + wm + (lane >> 4) * 4;
            #pragma unroll
            for (int im = 0; im < 2; im++)
                #pragma unroll
                for (int in = 0; in < 2; in++) {
                    int col = colb + in * 16;
                    float bv = p.ab1[col];
                    #pragma unroll
                    for (int q = 0; q < 4; q++)
                        p.s1[(rowb + im * 16 + q) * T_ + col] = f2bf(tanhf(acc[im][in][q] + bv));
                }
        } else if (t == 0) {
            if (blk == 36) {   // finalize alpha softmax over the 24 periods
                int b = tid;
                float v[24], mx = -INFINITY;
                #pragma unroll
                for (int k = 0; k < 24; k++) { v[k] = p.alpha[b * 24 + k]; mx = fmaxf(mx, v[k]); }
                float s = 0.f;
                #pragma unroll
                for (int k = 0; k < 24; k++) { v[k] = expf(v[k] - mx); s += v[k]; }
                float inv = 1.f / s;
                #pragma unroll
                for (int k = 0; k < 24; k++) p.alpha[b * 24 + k] = v[k] * inv;
            }
        } else if (blk < 52) {
            fc_tile(p, sm, blk - 36, t - 1, tid);
        }
        grid.sync();

        // ===== stage B: attn2 logits (blocks 0..35) =====
        if (blk < 36) {
            int n0 = (blk % 9) * 64, m0 = (blk / 9) * 64;
            f4 acc[2][2] = {};
            gemm64(p.s1 + m0 * T_, T_, p.W2b + n0 * T_, T_, T_,
                   sm.u.g.As, sm.u.g.Bs, tid, acc);
            int lane = tid & 63, w = tid >> 6;
            int wm = (w & 1) * 32, wn = (w >> 1) * 32;
            int colb = n0 + wn + (lane & 15);
            int rowb = m0 + wm + (lane >> 4) * 4;
            #pragma unroll
            for (int im = 0; im < 2; im++)
                #pragma unroll
                for (int in = 0; in < 2; in++) {
                    int col = colb + in * 16;
                    float bv = p.ab2[col];
                    #pragma unroll
                    for (int q = 0; q < 4; q++)
                        p.logit[(rowb + im * 16 + q) * T_ + col] = acc[im][in][q] + bv;
                }
        }
        grid.sync();

        // ===== stage C: softmax * alpha, weighted enc sum (all 256 blocks, 1 per batch) =====
        {
            int b = blk;
            const float* lg = p.logit + b * T_;
            float l0 = lg[tid], l1 = lg[tid + 256];
            float l2 = (tid < 64) ? lg[tid + 512] : -INFINITY;
            float mx = fmaxf(fmaxf(l0, l1), l2);
            for (int off = 32; off; off >>= 1) mx = fmaxf(mx, __shfl_xor(mx, off));
            if ((tid & 63) == 0) sm.u.c.red[tid >> 6] = mx;
            __syncthreads();
            mx = fmaxf(fmaxf(sm.u.c.red[0], sm.u.c.red[1]),
                       fmaxf(sm.u.c.red[2], sm.u.c.red[3]));
            float e0 = expf(l0 - mx), e1 = expf(l1 - mx);
            float e2 = (tid < 64) ? expf(l2 - mx) : 0.f;
            float s = e0 + e1 + e2;
            for (int off = 32; off; off >>= 1) s += __shfl_xor(s, off);
            __syncthreads();
            if ((tid & 63) == 0) sm.u.c.red[tid >> 6] = s;
            __syncthreads();
            float inv = 1.f / (sm.u.c.red[0] + sm.u.c.red[1] + sm.u.c.red[2] + sm.u.c.red[3]);
            const float* al = p.alpha + b * 24;
            sm.u.c.wt[tid]       = e0 * inv * al[tid / 24];
            sm.u.c.wt[tid + 256] = e1 * inv * al[(tid + 256) / 24];
            if (tid < 64) sm.u.c.wt[tid + 512] = e2 * inv * al[(tid + 512) / 24];
            __syncthreads();
            float a0 = 0.f, a1 = 0.f;
            const unsigned* ep = (const unsigned*)(p.encb + (size_t)b * T_ * E_) + tid;
            #pragma unroll 8
            for (int tt = 0; tt < T_; tt++) {
                float wv = sm.u.c.wt[tt];
                unsigned u = ep[(size_t)tt * (E_ / 2)];
                a0 += wv * bf2f((unsigned short)(u & 0xffffu));
                a1 += wv * bf2f((unsigned short)(u >> 16));
            }
            p.ctx[b * E_ + 2 * tid]     = a0;
            p.ctx[b * E_ + 2 * tid + 1] = a1;
        }
        grid.sync();

        // ===== stage D: gates GEMM (blocks 0..127) =====
        if (blk < 128) {
            int n0 = (blk & 31) * 64, m0 = (blk >> 5) * 64;
            int lane = tid & 63, w = tid >> 6;
            int wm = (w & 1) * 32, wn = (w >> 1) * 32;
            int r = tid >> 2, cg = (tid & 3) * 8;
            int fr = lane & 15, fk = (lane >> 4) * 8;
            f4 acc[2][2] = {};
            // phase 1: inp = [ctx | ff_t], K = 544
            for (int kc = 0; kc < KX_ / 32; kc++) {
                int k = kc * 32 + cg;
                union { short s[8]; int4 v; } av;
                if (k < E_) {
                    const float* c0 = p.ctx + (m0 + r) * E_ + k;
                    #pragma unroll
                    for (int j = 0; j < 8; j++) av.s[j] = f2bf(c0[j]);
                } else {
                    const float* fp = p.ff + ((m0 + r) * FT_ + t) * M_ + (k - E_);
                    #pragma unroll
                    for (int j = 0; j < 8; j++) av.s[j] = f2bf(fp[j]);
                }
                *(int4*)&sm.u.g.As[r][cg] = av.v;
                *(int4*)&sm.u.g.Bs[r][cg] = *(const int4*)(p.Wihb + (n0 + r) * KX_ + k);
                __syncthreads();
                bf8 a0 = *(const bf8*)&sm.u.g.As[wm + fr][fk];
                bf8 a1 = *(const bf8*)&sm.u.g.As[wm + 16 + fr][fk];
                bf8 b0 = *(const bf8*)&sm.u.g.Bs[wn + fr][fk];
                bf8 b1 = *(const bf8*)&sm.u.g.Bs[wn + 16 + fr][fk];
                acc[0][0] = __builtin_amdgcn_mfma_f32_16x16x32_bf16(a0, b0, acc[0][0], 0, 0, 0);
                acc[0][1] = __builtin_amdgcn_mfma_f32_16x16x32_bf16(a0, b1, acc[0][1], 0, 0, 0);
                acc[1][0] = __builtin_amdgcn_mfma_f32_16x16x32_bf16(a1, b0, acc[1][0], 0, 0, 0);
                acc[1][1] = __builtin_amdgcn_mfma_f32_16x16x32_bf16(a1, b1, acc[1][1], 0, 0, 0);
                __syncthreads();
            }
            // phase 2: + h[d] * Whh^T, K = 256  (h read straight out of xb)
            int d = n0 >> 10;
            gemm64(p.xb + m0 * KX_ + d * H_, KX_, p.Whhb + n0 * H_, H_, H_,
                   sm.u.g.As, sm.u.g.Bs, tid, acc);
            int colb = n0 + wn + (lane & 15);
            int rowb = m0 + wm + (lane >> 4) * 4;
            #pragma unroll
            for (int im = 0; im < 2; im++)
                #pragma unroll
                for (int in = 0; in < 2; in++)
                    #pragma unroll
                    for (int q = 0; q < 4; q++)
                        p.gates[(rowb + im * 16 + q) * ND_ + colb + in * 16] = acc[im][in][q];
        }
        grid.sync();

        // ===== stage E: LSTM pointwise; h -> xb; seed out with b2 (all blocks) =====
        #pragma unroll
        for (int half = 0; half < 2; half++) {
            int i = blk * 512 + half * 256 + tid;
            int d = i >> 16, b = (i >> 8) & 255, j = i & 255;
            int gb = b * ND_ + d * G_, bb = d * G_;
            float ig = p.gates[gb + j]       + p.bih[bb + j]       + p.bhh[bb + j];
            float fg = p.gates[gb + 256 + j] + p.bih[bb + 256 + j] + p.bhh[bb + 256 + j];
            float gg = p.gates[gb + 512 + j] + p.bih[bb + 512 + j] + p.bhh[bb + 512 + j];
            float og = p.gates[gb + 768 + j] + p.bih[bb + 768 + j] + p.bhh[bb + 768 + j];
            float cv = p.cbuf[i];
            float cn = sigm(fg) * cv + sigm(ig) * tanhf(gg);
            float hn = sigm(og) * tanhf(cn);
            p.cbuf[i] = cn;
            p.xb[b * KX_ + d * H_ + j] = f2bf(hn);
            if (d == 0) {
                if (j < M_ && t + 1 < FT_)
                    p.xb[b * KX_ + E_ + j] = f2bf(p.ff[(b * FT_ + t + 1) * M_ + j]);
                if (j == 0) p.out[b * FT_ + t] = p.fb2[0];
            }
        }
        grid.sync();
    }

    // tail: fc for the last step
    if (blk < 16) fc_tile(p, sm, blk, FT_ - 1, tid);
}

// ======================= fallback (non-cooperative) path =======================
__global__ __launch_bounds__(64) void k_alpha(const float* __restrict__ ff,
                                              const float* __restrict__ fhist,
                                              float* __restrict__ alpha) {
    int b = blockIdx.x;
    int t = threadIdx.x;
    float dp = 0.f;
    if (t < 24) {
        float fv[M_];
        const float* fp = ff + (b * FT_ + t) * M_;
        #pragma unroll
        for (int m = 0; m < M_; m++) fv[m] = fp[m];
        float dist = 0.f;
        for (int pp = 0; pp < 24; pp++) {
            const float* hp = fhist + (b * T_ + pp * 24 + t) * M_;
            float s = 0.f;
            #pragma unroll
            for (int m = 0; m < M_; m++) { float d = fv[m] - hp[m] + EPS_; s += d * d; }
            dist += sqrtf(s);
        }
        dp = 1.f / dist;
    }
    float v = (t < 24) ? dp : -INFINITY;
    float mx = v;
    for (int off = 32; off; off >>= 1) mx = fmaxf(mx, __shfl_xor(mx, off));
    float e = (t < 24) ? expf(dp - mx) : 0.f;
    float sme = e;
    for (int off = 32; off; off >>= 1) sme += __shfl_xor(sme, off);
    if (t < 24) alpha[b * 24 + t] = e / sme;
}

__global__ __launch_bounds__(256) void k_cast4(const float* __restrict__ src,
                                               short* __restrict__ dst, int n4) {
    int i = blockIdx.x * 256 + threadIdx.x;
    if (i < n4) {
        float4 v = ((const float4*)src)[i];
        short4 o;
        o.x = f2bf(v.x); o.y = f2bf(v.y); o.z = f2bf(v.z); o.w = f2bf(v.w);
        ((short4*)dst)[i] = o;
    }
}

__global__ __launch_bounds__(256) void k_init(const float* __restrict__ hidden,
                                              const float* __restrict__ cell,
                                              const float* __restrict__ ff,
                                              short* __restrict__ x, float* __restrict__ c) {
    int i = blockIdx.x * 256 + threadIdx.x;
    int d = i >> 16, b = (i >> 8) & 255, j = i & 255;
    x[b * KX_ + d * H_ + j] = f2bf(hidden[i]);
    c[i] = cell[i];
    if (d == 0 && j < M_) x[b * KX_ + E_ + j] = f2bf(ff[(b * FT_ + 0) * M_ + j]);
}

template <int EPI>   // 0 = tanh->bf16, 1 = fp32+bias
__global__ __launch_bounds__(256) void k_gemm(const short* __restrict__ A, int lda, int K,
                                              const short* __restrict__ W,
                                              const float* __restrict__ bias,
                                              void* __restrict__ out, int ldc) {
    __shared__ short As[64][40];
    __shared__ short Bs[64][40];
    int n0 = blockIdx.x * 64, m0 = blockIdx.y * 64;
    int tid = threadIdx.x;
    f4 acc[2][2] = {};
    gemm64(A + m0 * lda, lda, W + n0 * K, K, K, As, Bs, tid, acc);
    int lane = tid & 63, w = tid >> 6;
    int wm = (w & 1) * 32, wn = (w >> 1) * 32;
    int colb = n0 + wn + (lane & 15);
    int rowb = m0 + wm + (lane >> 4) * 4;
    #pragma unroll
    for (int im = 0; im < 2; im++)
        #pragma unroll
        for (int in = 0; in < 2; in++) {
            int col = colb + in * 16;
            float bv = bias[col];
            #pragma unroll
            for (int q = 0; q < 4; q++) {
                int row = rowb + im * 16 + q;
                float v = acc[im][in][q] + bv;
                if (EPI == 0) ((short*)out)[row * ldc + col] = f2bf(tanhf(v));
                else          ((float*)out)[row * ldc + col] = v;
            }
        }
}

__global__ __launch_bounds__(256) void k_ctx(const float* __restrict__ logits,
                                             const float* __restrict__ alpha,
                                             const short* __restrict__ encb,
                                             float* __restrict__ ctxp) {
    int b = blockIdx.x >> 2, s = blockIdx.x & 3;
    int tid = threadIdx.x;
    __shared__ float wt[T_];
    __shared__ float red[4];
    const float* lg = logits + b * T_;
    float l0 = lg[tid], l1 = lg[tid + 256];
    float l2 = (tid < 64) ? lg[tid + 512] : -INFINITY;
    float mx = fmaxf(fmaxf(l0, l1), l2);
    for (int off = 32; off; off >>= 1) mx = fmaxf(mx, __shfl_xor(mx, off));
    if ((tid & 63) == 0) red[tid >> 6] = mx;
    __syncthreads();
    mx = fmaxf(fmaxf(red[0], red[1]), fmaxf(red[2], red[3]));
    float e0 = expf(l0 - mx), e1 = expf(l1 - mx);
    float e2 = (tid < 64) ? expf(l2 - mx) : 0.f;
    float sme = e0 + e1 + e2;
    for (int off = 32; off; off >>= 1) sme += __shfl_xor(sme, off);
    __syncthreads();
    if ((tid & 63) == 0) red[tid >> 6] = sme;
    __syncthreads();
    float inv = 1.f / (red[0] + red[1] + red[2] + red[3]);
    const float* al = alpha + b * 24;
    wt[tid]       = e0 * inv * al[tid / 24];
    wt[tid + 256] = e1 * inv * al[(tid + 256) / 24];
    if (tid < 64) wt[tid + 512] = e2 * inv * al[(tid + 512) / 24];
    __syncthreads();
    float a0 = 0.f, a1 = 0.f;
    int t0 = s * (T_ / 4);
    const unsigned* ep = (const unsigned*)(encb + ((size_t)b * T_ + t0) * E_) + tid;
    for (int t = 0; t < T_ / 4; t++) {
        float wv = wt[t0 + t];
        unsigned u = ep[(size_t)t * (E_ / 2)];
        a0 += wv * bf2f((unsigned short)(u & 0xffffu));
        a1 += wv * bf2f((unsigned short)(u >> 16));
    }
    float* cp = ctxp + (s * B_ + b) * E_;
    cp[2 * tid] = a0;
    cp[2 * tid + 1] = a1;
}

__global__ __launch_bounds__(256) void k_gates(const float* __restrict__ ctxp,
                                               const float* __restrict__ ff, int step,
                                               const short* __restrict__ xb,
                                               const short* __restrict__ Wih,
                                               const short* __restrict__ Whh,
                                               float* __restrict__ gates) {
    __shared__ short As[64][40];
    __shared__ short Bs[64][40];
    int n0 = blockIdx.x * 64, m0 = blockIdx.y * 64;
    int tid = threadIdx.x, lane = tid & 63, w = tid >> 6;
    int wm = (w & 1) * 32, wn = (w >> 1) * 32;
    int r = tid >> 2, cg = (tid & 3) * 8;
    int b = m0 + r;
    f4 acc[2][2] = {};
    int fr = lane & 15, fk = (lane >> 4) * 8;
    for (int kc = 0; kc < KX_ / 32; kc++) {
        int k = kc * 32 + cg;
        union { short s[8]; int4 v; } av;
        if (k < E_) {
            const float* c0 = ctxp + b * E_ + k;
            #pragma unroll
            for (int j = 0; j < 8; j++) {
                float v = c0[j] + c0[B_ * E_ + j] + c0[2 * B_ * E_ + j] + c0[3 * B_ * E_ + j];
                av.s[j] = f2bf(v);
            }
        } else {
            const float* fp = ff + (b * FT_ + step) * M_ + (k - E_);
            #pragma unroll
            for (int j = 0; j < 8; j++) av.s[j] = f2bf(fp[j]);
        }
        *(int4*)&As[r][cg] = av.v;
        *(int4*)&Bs[r][cg] = *(const int4*)(Wih + (n0 + r) * KX_ + k);
        __syncthreads();
        bf8 a0 = *(const bf8*)&As[wm + fr][fk];
        bf8 a1 = *(const bf8*)&As[wm + 16 + fr][fk];
        bf8 b0 = *(const bf8*)&Bs[wn + fr][fk];
        bf8 b1 = *(const bf8*)&Bs[wn + 16 + fr][fk];
        acc[0][0] = __builtin_amdgcn_mfma_f32_16x16x32_bf16(a0, b0, acc[0][0], 0, 0, 0);
        acc[0][1] = __builtin_amdgcn_mfma_f32_16x16x32_bf16(a0, b1, acc[0][1], 0, 0, 0);
        acc[1][0] = __builtin_amdgcn_mfma_f32_16x16x32_bf16(a1, b0, acc[1][0], 0, 0, 0);
        acc[1][1] = __builtin_amdgcn_mfma_f32_16x16x32_bf16(a1, b1, acc[1][1], 0, 0, 0);
        __syncthreads();
    }
    int d = n0 >> 10;
    gemm64(xb + m0 * KX_ + d * H_, KX_, Whh + n0 * H_, H_, H_, As, Bs, tid, acc);
    int colb = n0 + wn + (lane & 15);
    int rowb = m0 + wm + (lane >> 4) * 4;
    #pragma unroll
    for (int im = 0; im < 2; im++)
        #pragma unroll
        for (int in = 0; in < 2; in++)
            #pragma unroll
            for (int q = 0; q < 4; q++)
                gates[(rowb + im * 16 + q) * ND_ + colb + in * 16] = acc[im][in][q];
}

__global__ __launch_bounds__(256) void k_lstm(const float* __restrict__ gates,
                                              const float* __restrict__ bih,
                                              const float* __restrict__ bhh,
                                              const float* __restrict__ ff, int step,
                                              float* __restrict__ c, short* __restrict__ x,
                                              const float* __restrict__ fb2,
                                              float* __restrict__ out) {
    int i = blockIdx.x * 256 + threadIdx.x;
    int d = i >> 16, b = (i >> 8) & 255, j = i & 255;
    int gb = b * ND_ + d * G_;
    int bb = d * G_;
    float ig = gates[gb + j]       + bih[bb + j]       + bhh[bb + j];
    float fg = gates[gb + 256 + j] + bih[bb + 256 + j] + bhh[bb + 256 + j];
    float gg = gates[gb + 512 + j] + bih[bb + 512 + j] + bhh[bb + 512 + j];
    float og = gates[gb + 768 + j] + bih[bb + 768 + j] + bhh[bb + 768 + j];
    float cv = c[i];
    float cn = sigm(fg) * cv + sigm(ig) * tanhf(gg);
    float hn = sigm(og) * tanhf(cn);
    c[i] = cn;
    x[b * KX_ + d * H_ + j] = f2bf(hn);
    if (d == 0) {
        if (j < M_ && step + 1 < FT_)
            x[b * KX_ + E_ + j] = f2bf(ff[(b * FT_ + step + 1) * M_ + j]);
        if (j == 0) out[b * FT_ + step] = fb2[0];
    }
}

__global__ __launch_bounds__(256) void k_fc(const short* __restrict__ xb,
                                            const short* __restrict__ fW1b,
                                            const float* __restrict__ fb1,
                                            const float* __restrict__ fW2,
                                            float* __restrict__ out, int step) {
    __shared__ short As[64][40];
    __shared__ short Bs[64][40];
    __shared__ float ypart[64];
    int fb = blockIdx.x, tid = threadIdx.x;
    int m0 = (fb >> 2) * 64, n0 = (fb & 3) * 64;
    f4 acc[2][2] = {};
    gemm64(xb + m0 * KX_, KX_, fW1b + n0 * E_, E_, E_, As, Bs, tid, acc);
    if (tid < 64) ypart[tid] = 0.f;
    __syncthreads();
    int lane = tid & 63, w = tid >> 6;
    int wm = (w & 1) * 32, wn = (w >> 1) * 32;
    int colb = n0 + wn + (lane & 15);
    int rloc = wm + (lane >> 4) * 4;
    #pragma unroll
    for (int im = 0; im < 2; im++)
        #pragma unroll
        for (int q = 0; q < 4; q++) {
            float s = 0.f;
            #pragma unroll
            for (int in = 0; in < 2; in++) {
                int col = colb + in * 16;
                s += fmaxf(acc[im][in][q] + fb1[col], 0.f) * fW2[col];
            }
            #pragma unroll
            for (int off = 1; off < 16; off <<= 1) s += __shfl_xor(s, off);
            if ((lane & 15) == 0) atomicAdd(&ypart[rloc + im * 16 + q], s);
        }
    __syncthreads();
    if (tid < 64) atomicAdd(&out[(m0 + tid) * FT_ + step], ypart[tid]);
}

extern "C" void kernel_launch(void* const* d_in, const int* in_sizes, int n_in,
                              void* d_out, int out_size, void* d_ws, size_t ws_size,
                              hipStream_t stream) {
    (void)in_sizes; (void)n_in; (void)out_size; (void)ws_size;
    const float* enc_f  = (const float*)d_in[0];
    const float* fhist  = (const float*)d_in[1];
    const float* ff     = (const float*)d_in[3];
    const float* hidden = (const float*)d_in[4];
    const float* cell   = (const float*)d_in[5];
    const float* aW1    = (const float*)d_in[6];
    const float* ab1    = (const float*)d_in[7];
    const float* aW2    = (const float*)d_in[8];
    const float* ab2    = (const float*)d_in[9];
    const float* Wih    = (const float*)d_in[10];
    const float* Whh    = (const float*)d_in[11];
    const float* bih    = (const float*)d_in[12];
    const float* bhh    = (const float*)d_in[13];
    const float* fW1    = (const float*)d_in[14];
    const float* fb1    = (const float*)d_in[15];
    const float* fW2    = (const float*)d_in[16];
    const float* fb2    = (const float*)d_in[17];
    float* out = (float*)d_out;

    char* pws = (char*)d_ws;
    auto take = [&](size_t n) { char* r = pws; pws += (n + 255) & ~(size_t)255; return r; };
    float* alpha = (float*)take(B_ * 24 * 4);
    short* xb    = (short*)take(B_ * KX_ * 2);
    float* cbuf  = (float*)take(2 * B_ * H_ * 4);
    short* s1    = (short*)take(B_ * T_ * 2);
    float* logit = (float*)take(B_ * T_ * 4);
    float* ctxp  = (float*)take(4 * B_ * E_ * 4);
    float* gates = (float*)take(B_ * ND_ * 4);
    short* W1b   = (short*)take(T_ * KX_ * 2);
    short* W2b   = (short*)take(T_ * T_ * 2);
    short* Wihb  = (short*)take(ND_ * KX_ * 2);
    short* Whhb  = (short*)take(ND_ * H_ * 2);
    short* fW1b  = (short*)take(H_ * E_ * 2);
    short* encb  = (short*)take((size_t)B_ * T_ * E_ * 2);

    Prm prm;
    prm.enc = enc_f; prm.fhist = fhist; prm.ff = ff; prm.hidden = hidden; prm.cell = cell;
    prm.aW1 = aW1; prm.ab1 = ab1; prm.aW2 = aW2; prm.ab2 = ab2;
    prm.Wih = Wih; prm.Whh = Whh; prm.bih = bih; prm.bhh = bhh;
    prm.fW1 = fW1; prm.fb1 = fb1; prm.fW2 = fW2; prm.fb2 = fb2;
    prm.out = out;
    prm.alpha = alpha; prm.cbuf = cbuf; prm.logit = logit; prm.ctx = ctxp; prm.gates = gates;
    prm.xb = xb; prm.s1 = s1; prm.W1b = W1b; prm.W2b = W2b;
    prm.Wihb = Wihb; prm.Whhb = Whhb; prm.fW1b = fW1b; prm.encb = encb;

    void* kargs[] = { (void*)&prm };
    hipError_t rc = hipLaunchCooperativeKernel((const void*)k_all, dim3(GRID_), dim3(256),
                                               kargs, 0, stream);
    if (rc == hipSuccess) return;

    // -------- fallback: multi-launch path (round-1 structure) --------
    k_alpha<<<B_, 64, 0, stream>>>(ff, fhist, alpha);
    k_cast4<<<(T_ * KX_ / 4 + 255) / 256, 256, 0, stream>>>(aW1, W1b, T_ * KX_ / 4);
    k_cast4<<<(T_ * T_ / 4 + 255) / 256, 256, 0, stream>>>(aW2, W2b, T_ * T_ / 4);
    k_cast4<<<(ND_ * KX_ / 4 + 255) / 256, 256, 0, stream>>>(Wih, Wihb, ND_ * KX_ / 4);
    k_cast4<<<(ND_ * H_ / 4 + 255) / 256, 256, 0, stream>>>(Whh, Whhb, ND_ * H_ / 4);
    k_cast4<<<(H_ * E_ / 4 + 255) / 256, 256, 0, stream>>>(fW1, fW1b, H_ * E_ / 4);
    k_cast4<<<(B_ * T_ * E_ / 4 + 255) / 256, 256, 0, stream>>>(enc_f, encb, B_ * T_ * E_ / 4);
    k_init<<<(2 * B_ * H_) / 256, 256, 0, stream>>>(hidden, cell, ff, xb, cbuf);
    for (int step = 0; step < FT_; step++) {
        k_gemm<0><<<dim3(T_ / 64, B_ / 64), 256, 0, stream>>>(xb, KX_, KX_, W1b, ab1, s1, T_);
        k_gemm<1><<<dim3(T_ / 64, B_ / 64), 256, 0, stream>>>(s1, T_, T_, W2b, ab2, logit, T_);
        k_ctx<<<B_ * 4, 256, 0, stream>>>(logit, alpha, encb, ctxp);
        k_gates<<<dim3(ND_ / 64, B_ / 64), 256, 0, stream>>>(ctxp, ff, step, xb, Wihb, Whhb, gates);
        k_lstm<<<(2 * B_ * H_) / 256, 256, 0, stream>>>(gates, bih, bhh, ff, step, cbuf, xb, fb2, out);
        k_fc<<<16, 256, 0, stream>>>(xb, fW1b, fb1, fW2, out, step);
    }
}

// Round 3
// 2396.552 us; speedup vs baseline: 2.3052x; 2.3052x over previous
//
#include <hip/hip_runtime.h>
#include <math.h>

#define B_ 256
#define T_ 576
#define FT_ 24
#define M_ 32
#define H_ 256
#define E_ 512
#define KX_ 544   // E + M
#define ND_ 2048  // 2*4H
#define EPS_ 1e-6f
#define LDAS 72   // 64 + 8 pad (shorts)

typedef __attribute__((ext_vector_type(8))) short bf8;   // 8 bf16 (4 VGPRs)
typedef __attribute__((ext_vector_type(4))) float f4;

__device__ __forceinline__ float bf2f(unsigned short s) {
    union { unsigned u; float f; } c; c.u = ((unsigned)s) << 16; return c.f;
}
__device__ __forceinline__ short f2bf(float f) {
    union { float f; unsigned u; } c; c.f = f;
    unsigned r = c.u + 0x7fffu + ((c.u >> 16) & 1u);
    return (short)(r >> 16);
}
__device__ __forceinline__ float sigm(float x) { return 1.f / (1.f + expf(-x)); }

__device__ __forceinline__ void mfma4(const short (*As)[LDAS], const short (*Bs)[LDAS],
                                      int wm, int wn, int fr, int fk, f4 acc[2][2]) {
    bf8 a0 = *(const bf8*)&As[wm + fr][fk];
    bf8 a1 = *(const bf8*)&As[wm + 16 + fr][fk];
    bf8 b0 = *(const bf8*)&Bs[wn + fr][fk];
    bf8 b1 = *(const bf8*)&Bs[wn + 16 + fr][fk];
    acc[0][0] = __builtin_amdgcn_mfma_f32_16x16x32_bf16(a0, b0, acc[0][0], 0, 0, 0);
    acc[0][1] = __builtin_amdgcn_mfma_f32_16x16x32_bf16(a0, b1, acc[0][1], 0, 0, 0);
    acc[1][0] = __builtin_amdgcn_mfma_f32_16x16x32_bf16(a1, b0, acc[1][0], 0, 0, 0);
    acc[1][1] = __builtin_amdgcn_mfma_f32_16x16x32_bf16(a1, b1, acc[1][1], 0, 0, 0);
}

// 64x64 output tile GEMM, BK=64 (tail 32 ok): acc += A[64xK] * Wt[64xK]^T
__device__ __forceinline__ void gemm64(const short* __restrict__ A, int lda,
                                       const short* __restrict__ Wt, int ldw, int K,
                                       short (*As)[LDAS], short (*Bs)[LDAS], int tid,
                                       f4 acc[2][2]) {
    int lane = tid & 63, w = tid >> 6;
    int wm = (w & 1) * 32, wn = (w >> 1) * 32;
    int fr = lane & 15, fk = (lane >> 4) * 8;
    int r = tid >> 2, c0 = (tid & 3) * 16, c8 = (tid & 3) * 8;
    int4 pa0, pa1, pb0, pb1;
    auto ld = [&](int k0) {
        if (K - k0 >= 64) {
            pa0 = *(const int4*)(A + r * lda + k0 + c0);
            pa1 = *(const int4*)(A + r * lda + k0 + c0 + 8);
            pb0 = *(const int4*)(Wt + r * ldw + k0 + c0);
            pb1 = *(const int4*)(Wt + r * ldw + k0 + c0 + 8);
        } else {
            pa0 = *(const int4*)(A + r * lda + k0 + c8);
            pb0 = *(const int4*)(Wt + r * ldw + k0 + c8);
        }
    };
    ld(0);
    for (int k0 = 0; k0 < K; k0 += 64) {
        int rem = K - k0;
        if (rem >= 64) {
            *(int4*)&As[r][c0] = pa0; *(int4*)&As[r][c0 + 8] = pa1;
            *(int4*)&Bs[r][c0] = pb0; *(int4*)&Bs[r][c0 + 8] = pb1;
        } else {
            *(int4*)&As[r][c8] = pa0;
            *(int4*)&Bs[r][c8] = pb0;
        }
        __syncthreads();
        if (k0 + 64 < K) ld(k0 + 64);
        mfma4(As, Bs, wm, wn, fr, fk, acc);
        if (rem >= 64) mfma4(As, Bs, wm, wn, fr, fk + 32, acc);
        __syncthreads();
    }
}

// ---------------- fused setup: casts, gate-permuted weights, bias, alpha, init ----------------
struct SetupPrm {
    const float *enc, *fhist, *ff, *hidden, *cell;
    const float *aW1, *aW2, *Wih, *Whh, *bih, *bhh, *fW1;
    short *W1b, *W2b, *Wihb, *Whhb, *fW1b, *encb, *xb, *hA;
    float *bcomb, *alpha, *cbuf;
};

__global__ __launch_bounds__(256) void k_setup(SetupPrm p) {
    const int NT = 2048 * 256;
    int gt = blockIdx.x * 256 + threadIdx.x;
    auto cast = [&](const float* s, short* d, int n4) {
        for (int i = gt; i < n4; i += NT) {
            float4 v = ((const float4*)s)[i];
            short4 o; o.x = f2bf(v.x); o.y = f2bf(v.y); o.z = f2bf(v.z); o.w = f2bf(v.w);
            ((short4*)d)[i] = o;
        }
    };
    cast(p.aW1, p.W1b, T_ * KX_ / 4);
    cast(p.aW2, p.W2b, T_ * T_ / 4);
    cast(p.fW1, p.fW1b, H_ * E_ / 4);
    cast(p.enc, p.encb, B_ * T_ * E_ / 4);
    // gate-permuted Wih: new row d*1024 + j*4 + g  <-  orig d*1024 + g*256 + j
    for (int i = gt; i < ND_ * KX_ / 4; i += NT) {
        int row = i / (KX_ / 4), c4 = i % (KX_ / 4);
        int d = row >> 10, rest = row & 1023, j = rest >> 2, g = rest & 3;
        int orig = d * 1024 + g * 256 + j;
        float4 v = ((const float4*)(p.Wih + orig * KX_))[c4];
        short4 o; o.x = f2bf(v.x); o.y = f2bf(v.y); o.z = f2bf(v.z); o.w = f2bf(v.w);
        ((short4*)(p.Wihb + row * KX_))[c4] = o;
    }
    for (int i = gt; i < ND_ * H_ / 4; i += NT) {
        int row = i / (H_ / 4), c4 = i % (H_ / 4);
        int d = row >> 10, rest = row & 1023, j = rest >> 2, g = rest & 3;
        int orig = d * 1024 + g * 256 + j;
        float4 v = ((const float4*)(p.Whh + orig * H_))[c4];
        short4 o; o.x = f2bf(v.x); o.y = f2bf(v.y); o.z = f2bf(v.z); o.w = f2bf(v.w);
        ((short4*)(p.Whhb + row * H_))[c4] = o;
    }
    for (int i = gt; i < ND_; i += NT) {
        int d = i >> 10, rest = i & 1023, j = rest >> 2, g = rest & 3;
        int orig = d * 1024 + g * 256 + j;
        p.bcomb[i] = p.bih[orig] + p.bhh[orig];
    }
    // init: x0 = [h0|h1|ff0] bf16, hA = h0 bf16, c fp32
    for (int i = gt; i < 2 * B_ * H_; i += NT) {
        int d = i >> 16, b = (i >> 8) & 255, j = i & 255;
        short hv = f2bf(p.hidden[i]);
        p.xb[b * KX_ + d * H_ + j] = hv;
        p.hA[i] = hv;                       // layout [d][b][j] == flat i
        p.cbuf[i] = p.cell[i];
        if (d == 0 && j < M_) p.xb[b * KX_ + E_ + j] = f2bf(p.ff[b * FT_ * M_ + j]);
    }
    // alpha softmax (one wave per batch, blocks 0..255)
    if (blockIdx.x < 256 && threadIdx.x < 64) {
        int b = blockIdx.x, t = threadIdx.x;
        float dp = 0.f;
        if (t < 24) {
            float fv[M_];
            const float* fp = p.ff + (b * FT_ + t) * M_;
            #pragma unroll
            for (int m = 0; m < M_; m++) fv[m] = fp[m];
            float dist = 0.f;
            for (int pp = 0; pp < 24; pp++) {
                const float* hp = p.fhist + (b * T_ + pp * 24 + t) * M_;
                float s = 0.f;
                #pragma unroll
                for (int m = 0; m < M_; m++) { float d = fv[m] - hp[m] + EPS_; s += d * d; }
                dist += sqrtf(s);
            }
            dp = 1.f / dist;
        }
        float v = (t < 24) ? dp : -INFINITY;
        float mx = v;
        for (int off = 32; off; off >>= 1) mx = fmaxf(mx, __shfl_xor(mx, off));
        float e = (t < 24) ? expf(dp - mx) : 0.f;
        float sme = e;
        for (int off = 32; off; off >>= 1) sme += __shfl_xor(sme, off);
        if (t < 24) p.alpha[b * 24 + t] = e / sme;
    }
}

// ---------------- attn GEMMs: EPI 0 = tanh->bf16, 1 = +bias fp32 ----------------
template <int EPI>
__global__ __launch_bounds__(256) void k_gemm(const short* __restrict__ A, int lda, int K,
                                              const short* __restrict__ W,
                                              const float* __restrict__ bias,
                                              void* __restrict__ out, int ldc) {
    __shared__ short As[64][LDAS];
    __shared__ short Bs[64][LDAS];
    int n0 = blockIdx.x * 64, m0 = blockIdx.y * 64, tid = threadIdx.x;
    f4 acc[2][2] = {};
    gemm64(A + m0 * lda, lda, W + n0 * K, K, K, As, Bs, tid, acc);
    int lane = tid & 63, w = tid >> 6;
    int wm = (w & 1) * 32, wn = (w >> 1) * 32;
    int colb = n0 + wn + (lane & 15);
    int rowb = m0 + wm + (lane >> 4) * 4;
    #pragma unroll
    for (int im = 0; im < 2; im++)
        #pragma unroll
        for (int in = 0; in < 2; in++) {
            int col = colb + in * 16;
            float bv = bias[col];
            #pragma unroll
            for (int q = 0; q < 4; q++) {
                int row = rowb + im * 16 + q;
                float v = acc[im][in][q] + bv;
                if (EPI == 0) ((short*)out)[row * ldc + col] = f2bf(tanhf(v));
                else          ((float*)out)[row * ldc + col] = v;
            }
        }
}

// ---------------- softmax*alpha + weighted enc sum; 4 t-slices per batch ----------------
__global__ __launch_bounds__(256) void k_ctx(const float* __restrict__ logits,
                                             const float* __restrict__ alpha,
                                             const short* __restrict__ encb,
                                             float* __restrict__ ctxp) {
    int b = blockIdx.x >> 2, s = blockIdx.x & 3;
    int tid = threadIdx.x;
    __shared__ float wt[T_];
    __shared__ float red[4];
    const float* lg = logits + b * T_;
    float l0 = lg[tid], l1 = lg[tid + 256];
    float l2 = (tid < 64) ? lg[tid + 512] : -INFINITY;
    float mx = fmaxf(fmaxf(l0, l1), l2);
    for (int off = 32; off; off >>= 1) mx = fmaxf(mx, __shfl_xor(mx, off));
    if ((tid & 63) == 0) red[tid >> 6] = mx;
    __syncthreads();
    mx = fmaxf(fmaxf(red[0], red[1]), fmaxf(red[2], red[3]));
    float e0 = expf(l0 - mx), e1 = expf(l1 - mx);
    float e2 = (tid < 64) ? expf(l2 - mx) : 0.f;
    float sme = e0 + e1 + e2;
    for (int off = 32; off; off >>= 1) sme += __shfl_xor(sme, off);
    __syncthreads();
    if ((tid & 63) == 0) red[tid >> 6] = sme;
    __syncthreads();
    float inv = 1.f / (red[0] + red[1] + red[2] + red[3]);
    const float* al = alpha + b * 24;
    wt[tid]       = e0 * inv * al[tid / 24];
    wt[tid + 256] = e1 * inv * al[(tid + 256) / 24];
    if (tid < 64) wt[tid + 512] = e2 * inv * al[(tid + 512) / 24];
    __syncthreads();
    float a0 = 0.f, a1 = 0.f;
    int t0 = s * (T_ / 4);
    const unsigned* ep = (const unsigned*)(encb + ((size_t)b * T_ + t0) * E_) + tid;
    #pragma unroll 8
    for (int t = 0; t < T_ / 4; t++) {
        float wv = wt[t0 + t];
        unsigned u = ep[(size_t)t * (E_ / 2)];
        a0 += wv * bf2f((unsigned short)(u & 0xffffu));
        a1 += wv * bf2f((unsigned short)(u >> 16));
    }
    float* cp = ctxp + (s * B_ + b) * E_;
    cp[2 * tid] = a0;
    cp[2 * tid + 1] = a1;
}

// ---------------- gates GEMM (gate-permuted cols) + fused LSTM pointwise ----------------
__global__ __launch_bounds__(256) void k_gl(const float* __restrict__ ctxp,
                                            const float* __restrict__ ff, int t,
                                            short* __restrict__ xb,
                                            const short* __restrict__ Wihb,
                                            const short* __restrict__ Whhb,
                                            const float* __restrict__ bcomb,
                                            float* __restrict__ cbuf,
                                            const short* __restrict__ hprev,
                                            short* __restrict__ hnext,
                                            const float* __restrict__ fb2,
                                            float* __restrict__ out) {
    __shared__ union {
        struct { short As[64][LDAS]; short Bs[64][LDAS]; } g;
        float gt[64][68];
    } sm;
    int n0 = blockIdx.x * 64, m0 = blockIdx.y * 64, tid = threadIdx.x;
    int lane = tid & 63, w = tid >> 6;
    int wm = (w & 1) * 32, wn = (w >> 1) * 32;
    int fr = lane & 15, fk = (lane >> 4) * 8;
    int r = tid >> 2, c0 = (tid & 3) * 16, c8 = (tid & 3) * 8;
    f4 acc[2][2] = {};
    // phase 1: inp = [ctx(sum 4 partials) | ff_t], K = 544
    for (int k0 = 0; k0 < KX_; k0 += 64) {
        int rem = KX_ - k0;
        if (rem >= 64) {
            const float* cp = ctxp + (m0 + r) * E_ + k0 + c0;
            short av[16];
            #pragma unroll
            for (int i = 0; i < 16; i++)
                av[i] = f2bf(cp[i] + cp[B_ * E_ + i] + cp[2 * B_ * E_ + i] + cp[3 * B_ * E_ + i]);
            *(int4*)&sm.g.As[r][c0]     = *(int4*)&av[0];
            *(int4*)&sm.g.As[r][c0 + 8] = *(int4*)&av[8];
            *(int4*)&sm.g.Bs[r][c0]     = *(const int4*)(Wihb + (n0 + r) * KX_ + k0 + c0);
            *(int4*)&sm.g.Bs[r][c0 + 8] = *(const int4*)(Wihb + (n0 + r) * KX_ + k0 + c0 + 8);
        } else {
            const float* fp = ff + ((m0 + r) * FT_ + t) * M_ + (k0 + c8 - E_);
            short av[8];
            #pragma unroll
            for (int i = 0; i < 8; i++) av[i] = f2bf(fp[i]);
            *(int4*)&sm.g.As[r][c8] = *(int4*)&av[0];
            *(int4*)&sm.g.Bs[r][c8] = *(const int4*)(Wihb + (n0 + r) * KX_ + k0 + c8);
        }
        __syncthreads();
        mfma4(sm.g.As, sm.g.Bs, wm, wn, fr, fk, acc);
        if (rem >= 64) mfma4(sm.g.As, sm.g.Bs, wm, wn, fr, fk + 32, acc);
        __syncthreads();
    }
    // phase 2: + h_{t-1}[d] * Whh^T, K = 256
    int d = n0 >> 10;
    gemm64(hprev + d * B_ * H_ + m0 * H_, H_, Whhb + n0 * H_, H_, H_,
           sm.g.As, sm.g.Bs, tid, acc);
    // epilogue: +bias -> LDS, then LSTM pointwise
    int clb = wn + (lane & 15);
    int rlb = wm + (lane >> 4) * 4;
    #pragma unroll
    for (int im = 0; im < 2; im++)
        #pragma unroll
        for (int in = 0; in < 2; in++) {
            int cl = clb + in * 16;
            float bv = bcomb[n0 + cl];
            #pragma unroll
            for (int q = 0; q < 4; q++)
                sm.gt[rlb + im * 16 + q][cl] = acc[im][in][q] + bv;
        }
    __syncthreads();
    int j0 = (n0 >> 2) & 255;
    #pragma unroll
    for (int it = 0; it < 4; it++) {
        int item = tid + it * 256;
        int rl = item >> 4, ql = item & 15;
        float ig = sm.gt[rl][ql * 4 + 0];
        float fg = sm.gt[rl][ql * 4 + 1];
        float gg = sm.gt[rl][ql * 4 + 2];
        float og = sm.gt[rl][ql * 4 + 3];
        int b = m0 + rl, j = j0 + ql;
        int ci = d * 65536 + b * 256 + j;
        float cn = sigm(fg) * cbuf[ci] + sigm(ig) * tanhf(gg);
        float hn = sigm(og) * tanhf(cn);
        cbuf[ci] = cn;
        short hv = f2bf(hn);
        xb[b * KX_ + d * H_ + j] = hv;
        hnext[ci] = hv;
        if (d == 0 && j < M_ && t + 1 < FT_)
            xb[b * KX_ + E_ + j] = f2bf(ff[(b * FT_ + t + 1) * M_ + j]);
        if (n0 == 0 && ql == 0) out[b * FT_ + t] = fb2[0];
    }
}

// ---------------- fused fc1(relu) + fc2 dot ----------------
__global__ __launch_bounds__(256) void k_fc(const short* __restrict__ xb,
                                            const short* __restrict__ fW1b,
                                            const float* __restrict__ fb1,
                                            const float* __restrict__ fW2,
                                            float* __restrict__ out, int step) {
    __shared__ short As[64][LDAS];
    __shared__ short Bs[64][LDAS];
    __shared__ float ypart[64];
    int fb = blockIdx.x, tid = threadIdx.x;
    int m0 = (fb >> 2) * 64, n0 = (fb & 3) * 64;
    f4 acc[2][2] = {};
    gemm64(xb + m0 * KX_, KX_, fW1b + n0 * E_, E_, E_, As, Bs, tid, acc);
    if (tid < 64) ypart[tid] = 0.f;
    __syncthreads();
    int lane = tid & 63, w = tid >> 6;
    int wm = (w & 1) * 32, wn = (w >> 1) * 32;
    int colb = n0 + wn + (lane & 15);
    int rloc = wm + (lane >> 4) * 4;
    #pragma unroll
    for (int im = 0; im < 2; im++)
        #pragma unroll
        for (int q = 0; q < 4; q++) {
            float s = 0.f;
            #pragma unroll
            for (int in = 0; in < 2; in++) {
                int col = colb + in * 16;
                s += fmaxf(acc[im][in][q] + fb1[col], 0.f) * fW2[col];
            }
            #pragma unroll
            for (int off = 1; off < 16; off <<= 1) s += __shfl_xor(s, off);
            if ((lane & 15) == 0) atomicAdd(&ypart[rloc + im * 16 + q], s);
        }
    __syncthreads();
    if (tid < 64) atomicAdd(&out[(m0 + tid) * FT_ + step], ypart[tid]);
}

extern "C" void kernel_launch(void* const* d_in, const int* in_sizes, int n_in,
                              void* d_out, int out_size, void* d_ws, size_t ws_size,
                              hipStream_t stream) {
    (void)in_sizes; (void)n_in; (void)out_size; (void)ws_size;
    const float* enc_f  = (const float*)d_in[0];
    const float* fhist  = (const float*)d_in[1];
    const float* ff     = (const float*)d_in[3];
    const float* hidden = (const float*)d_in[4];
    const float* cell   = (const float*)d_in[5];
    const float* aW1    = (const float*)d_in[6];
    const float* ab1    = (const float*)d_in[7];
    const float* aW2    = (const float*)d_in[8];
    const float* ab2    = (const float*)d_in[9];
    const float* Wih    = (const float*)d_in[10];
    const float* Whh    = (const float*)d_in[11];
    const float* bih    = (const float*)d_in[12];
    const float* bhh    = (const float*)d_in[13];
    const float* fW1    = (const float*)d_in[14];
    const float* fb1    = (const float*)d_in[15];
    const float* fW2    = (const float*)d_in[16];
    const float* fb2    = (const float*)d_in[17];
    float* out = (float*)d_out;

    char* pws = (char*)d_ws;
    auto take = [&](size_t n) { char* r = pws; pws += (n + 255) & ~(size_t)255; return r; };
    float* alpha = (float*)take(B_ * 24 * 4);
    short* xb    = (short*)take(B_ * KX_ * 2);
    short* hA    = (short*)take(2 * B_ * H_ * 2);
    short* hB    = (short*)take(2 * B_ * H_ * 2);
    float* cbuf  = (float*)take(2 * B_ * H_ * 4);
    short* s1    = (short*)take(B_ * T_ * 2);
    float* logit = (float*)take(B_ * T_ * 4);
    float* ctxp  = (float*)take(4 * B_ * E_ * 4);
    float* bcomb = (float*)take(ND_ * 4);
    short* W1b   = (short*)take(T_ * KX_ * 2);
    short* W2b   = (short*)take(T_ * T_ * 2);
    short* Wihb  = (short*)take(ND_ * KX_ * 2);
    short* Whhb  = (short*)take(ND_ * H_ * 2);
    short* fW1b  = (short*)take(H_ * E_ * 2);
    short* encb  = (short*)take((size_t)B_ * T_ * E_ * 2);

    SetupPrm sp;
    sp.enc = enc_f; sp.fhist = fhist; sp.ff = ff; sp.hidden = hidden; sp.cell = cell;
    sp.aW1 = aW1; sp.aW2 = aW2; sp.Wih = Wih; sp.Whh = Whh; sp.bih = bih; sp.bhh = bhh;
    sp.fW1 = fW1;
    sp.W1b = W1b; sp.W2b = W2b; sp.Wihb = Wihb; sp.Whhb = Whhb; sp.fW1b = fW1b;
    sp.encb = encb; sp.xb = xb; sp.hA = hA;
    sp.bcomb = bcomb; sp.alpha = alpha; sp.cbuf = cbuf;

    k_setup<<<2048, 256, 0, stream>>>(sp);

    for (int t = 0; t < FT_; t++) {
        k_gemm<0><<<dim3(T_ / 64, B_ / 64), 256, 0, stream>>>(xb, KX_, KX_, W1b, ab1, s1, T_);
        k_gemm<1><<<dim3(T_ / 64, B_ / 64), 256, 0, stream>>>(s1, T_, T_, W2b, ab2, logit, T_);
        k_ctx<<<B_ * 4, 256, 0, stream>>>(logit, alpha, encb, ctxp);
        const short* hprev = (t & 1) ? hB : hA;
        short* hnext       = (t & 1) ? hA : hB;
        k_gl<<<dim3(ND_ / 64, B_ / 64), 256, 0, stream>>>(ctxp, ff, t, xb, Wihb, Whhb,
                                                          bcomb, cbuf, hprev, hnext, fb2, out);
        k_fc<<<16, 256, 0, stream>>>(xb, fW1b, fb1, fW2, out, t);
    }
}

// Round 4
// 1860.502 us; speedup vs baseline: 2.9694x; 1.2881x over previous
//
#include <hip/hip_runtime.h>
#include <math.h>

#define B_ 256
#define T_ 576
#define FT_ 24
#define M_ 32
#define H_ 256
#define E_ 512
#define KX_ 544   // E + M
#define ND_ 2048  // 2*4H
#define EPS_ 1e-6f
#define LDAS 72   // 64 + 8 pad (shorts)

typedef __attribute__((ext_vector_type(8))) short bf8;   // 8 bf16 (4 VGPRs)
typedef __attribute__((ext_vector_type(4))) float f4;

__device__ __forceinline__ float bf2f(unsigned short s) {
    union { unsigned u; float f; } c; c.u = ((unsigned)s) << 16; return c.f;
}
__device__ __forceinline__ short f2bf(float f) {
    union { float f; unsigned u; } c; c.f = f;
    unsigned r = c.u + 0x7fffu + ((c.u >> 16) & 1u);
    return (short)(r >> 16);
}
__device__ __forceinline__ float sigm(float x) { return 1.f / (1.f + expf(-x)); }

__device__ __forceinline__ void mfma4(const short (*As)[LDAS], const short (*Bs)[LDAS],
                                      int wm, int wn, int fr, int fk, f4 acc[2][2]) {
    bf8 a0 = *(const bf8*)&As[wm + fr][fk];
    bf8 a1 = *(const bf8*)&As[wm + 16 + fr][fk];
    bf8 b0 = *(const bf8*)&Bs[wn + fr][fk];
    bf8 b1 = *(const bf8*)&Bs[wn + 16 + fr][fk];
    acc[0][0] = __builtin_amdgcn_mfma_f32_16x16x32_bf16(a0, b0, acc[0][0], 0, 0, 0);
    acc[0][1] = __builtin_amdgcn_mfma_f32_16x16x32_bf16(a0, b1, acc[0][1], 0, 0, 0);
    acc[1][0] = __builtin_amdgcn_mfma_f32_16x16x32_bf16(a1, b0, acc[1][0], 0, 0, 0);
    acc[1][1] = __builtin_amdgcn_mfma_f32_16x16x32_bf16(a1, b1, acc[1][1], 0, 0, 0);
}

// 64x64 output tile GEMM, BK=64 (tail 32 ok): acc += A[64xK] * Wt[64xK]^T
__device__ __forceinline__ void gemm64(const short* __restrict__ A, int lda,
                                       const short* __restrict__ Wt, int ldw, int K,
                                       short (*As)[LDAS], short (*Bs)[LDAS], int tid,
                                       f4 acc[2][2]) {
    int lane = tid & 63, w = tid >> 6;
    int wm = (w & 1) * 32, wn = (w >> 1) * 32;
    int fr = lane & 15, fk = (lane >> 4) * 8;
    int r = tid >> 2, c0 = (tid & 3) * 16, c8 = (tid & 3) * 8;
    int4 pa0, pa1, pb0, pb1;
    auto ld = [&](int k0) {
        if (K - k0 >= 64) {
            pa0 = *(const int4*)(A + r * lda + k0 + c0);
            pa1 = *(const int4*)(A + r * lda + k0 + c0 + 8);
            pb0 = *(const int4*)(Wt + r * ldw + k0 + c0);
            pb1 = *(const int4*)(Wt + r * ldw + k0 + c0 + 8);
        } else {
            pa0 = *(const int4*)(A + r * lda + k0 + c8);
            pb0 = *(const int4*)(Wt + r * ldw + k0 + c8);
        }
    };
    ld(0);
    for (int k0 = 0; k0 < K; k0 += 64) {
        int rem = K - k0;
        if (rem >= 64) {
            *(int4*)&As[r][c0] = pa0; *(int4*)&As[r][c0 + 8] = pa1;
            *(int4*)&Bs[r][c0] = pb0; *(int4*)&Bs[r][c0 + 8] = pb1;
        } else {
            *(int4*)&As[r][c8] = pa0;
            *(int4*)&Bs[r][c8] = pb0;
        }
        __syncthreads();
        if (k0 + 64 < K) ld(k0 + 64);
        mfma4(As, Bs, wm, wn, fr, fk, acc);
        if (rem >= 64) mfma4(As, Bs, wm, wn, fr, fk + 32, acc);
        __syncthreads();
    }
}

// ---------------- fused setup: casts, gate-permuted weights, bias, alpha, init ----------------
struct SetupPrm {
    const float *enc, *fhist, *ff, *hidden, *cell;
    const float *aW1, *aW2, *Wih, *Whh, *bih, *bhh, *fW1;
    short *W1b, *W2b, *Wihb, *Whhb, *fW1b, *encb, *xb, *hA;
    float *bcomb, *alpha, *cbuf;
};

__global__ __launch_bounds__(256) void k_setup(SetupPrm p) {
    const int NT = 2048 * 256;
    int gt = blockIdx.x * 256 + threadIdx.x;
    auto cast = [&](const float* s, short* d, int n4) {
        for (int i = gt; i < n4; i += NT) {
            float4 v = ((const float4*)s)[i];
            short4 o; o.x = f2bf(v.x); o.y = f2bf(v.y); o.z = f2bf(v.z); o.w = f2bf(v.w);
            ((short4*)d)[i] = o;
        }
    };
    cast(p.aW1, p.W1b, T_ * KX_ / 4);
    cast(p.aW2, p.W2b, T_ * T_ / 4);
    cast(p.fW1, p.fW1b, H_ * E_ / 4);
    cast(p.enc, p.encb, B_ * T_ * E_ / 4);
    // gate-permuted Wih: new row d*1024 + j*4 + g  <-  orig d*1024 + g*256 + j
    for (int i = gt; i < ND_ * KX_ / 4; i += NT) {
        int row = i / (KX_ / 4), c4 = i % (KX_ / 4);
        int d = row >> 10, rest = row & 1023, j = rest >> 2, g = rest & 3;
        int orig = d * 1024 + g * 256 + j;
        float4 v = ((const float4*)(p.Wih + orig * KX_))[c4];
        short4 o; o.x = f2bf(v.x); o.y = f2bf(v.y); o.z = f2bf(v.z); o.w = f2bf(v.w);
        ((short4*)(p.Wihb + row * KX_))[c4] = o;
    }
    for (int i = gt; i < ND_ * H_ / 4; i += NT) {
        int row = i / (H_ / 4), c4 = i % (H_ / 4);
        int d = row >> 10, rest = row & 1023, j = rest >> 2, g = rest & 3;
        int orig = d * 1024 + g * 256 + j;
        float4 v = ((const float4*)(p.Whh + orig * H_))[c4];
        short4 o; o.x = f2bf(v.x); o.y = f2bf(v.y); o.z = f2bf(v.z); o.w = f2bf(v.w);
        ((short4*)(p.Whhb + row * H_))[c4] = o;
    }
    for (int i = gt; i < ND_; i += NT) {
        int d = i >> 10, rest = i & 1023, j = rest >> 2, g = rest & 3;
        int orig = d * 1024 + g * 256 + j;
        p.bcomb[i] = p.bih[orig] + p.bhh[orig];
    }
    // init: x0 = [h0|h1|ff0] bf16, hA = h0 bf16, c fp32
    for (int i = gt; i < 2 * B_ * H_; i += NT) {
        int d = i >> 16, b = (i >> 8) & 255, j = i & 255;
        short hv = f2bf(p.hidden[i]);
        p.xb[b * KX_ + d * H_ + j] = hv;
        p.hA[i] = hv;                       // layout [d][b][j] == flat i
        p.cbuf[i] = p.cell[i];
        if (d == 0 && j < M_) p.xb[b * KX_ + E_ + j] = f2bf(p.ff[b * FT_ * M_ + j]);
    }
    // alpha softmax (one wave per batch, blocks 0..255)
    if (blockIdx.x < 256 && threadIdx.x < 64) {
        int b = blockIdx.x, t = threadIdx.x;
        float dp = 0.f;
        if (t < 24) {
            float fv[M_];
            const float* fp = p.ff + (b * FT_ + t) * M_;
            #pragma unroll
            for (int m = 0; m < M_; m++) fv[m] = fp[m];
            float dist = 0.f;
            for (int pp = 0; pp < 24; pp++) {
                const float* hp = p.fhist + (b * T_ + pp * 24 + t) * M_;
                float s = 0.f;
                #pragma unroll
                for (int m = 0; m < M_; m++) { float d = fv[m] - hp[m] + EPS_; s += d * d; }
                dist += sqrtf(s);
            }
            dp = 1.f / dist;
        }
        float v = (t < 24) ? dp : -INFINITY;
        float mx = v;
        for (int off = 32; off; off >>= 1) mx = fmaxf(mx, __shfl_xor(mx, off));
        float e = (t < 24) ? expf(dp - mx) : 0.f;
        float sme = e;
        for (int off = 32; off; off >>= 1) sme += __shfl_xor(sme, off);
        if (t < 24) p.alpha[b * 24 + t] = e / sme;
    }
}

// ---------------- attn1 (tanh->bf16) fused with fc of previous step ----------------
// grid (13, 4): x<9 -> attn1 tile; x>=9 -> fc tile (x-9 = n-tile, y = m-tile)
__global__ __launch_bounds__(256) void k_a1fc(const short* __restrict__ xb,
                                              const short* __restrict__ W1b,
                                              const float* __restrict__ ab1,
                                              short* __restrict__ s1,
                                              const short* __restrict__ fW1b,
                                              const float* __restrict__ fb1,
                                              const float* __restrict__ fW2,
                                              float* __restrict__ out, int t) {
    __shared__ short As[64][LDAS];
    __shared__ short Bs[64][LDAS];
    __shared__ float ypart[64];
    int tid = threadIdx.x;
    int lane = tid & 63, w = tid >> 6;
    int wm = (w & 1) * 32, wn = (w >> 1) * 32;
    int m0 = blockIdx.y * 64;
    if (blockIdx.x < 9) {
        int n0 = blockIdx.x * 64;
        f4 acc[2][2] = {};
        gemm64(xb + m0 * KX_, KX_, W1b + n0 * KX_, KX_, KX_, As, Bs, tid, acc);
        int colb = n0 + wn + (lane & 15);
        int rowb = m0 + wm + (lane >> 4) * 4;
        #pragma unroll
        for (int im = 0; im < 2; im++)
            #pragma unroll
            for (int in = 0; in < 2; in++) {
                int col = colb + in * 16;
                float bv = ab1[col];
                #pragma unroll
                for (int q = 0; q < 4; q++)
                    s1[(rowb + im * 16 + q) * T_ + col] = f2bf(tanhf(acc[im][in][q] + bv));
            }
    } else {
        if (t == 0) return;            // no previous step yet
        int step = t - 1;
        int n0 = (blockIdx.x - 9) * 64;
        f4 acc[2][2] = {};
        gemm64(xb + m0 * KX_, KX_, fW1b + n0 * E_, E_, E_, As, Bs, tid, acc);
        if (tid < 64) ypart[tid] = 0.f;
        __syncthreads();
        int colb = n0 + wn + (lane & 15);
        int rloc = wm + (lane >> 4) * 4;
        #pragma unroll
        for (int im = 0; im < 2; im++)
            #pragma unroll
            for (int q = 0; q < 4; q++) {
                float s = 0.f;
                #pragma unroll
                for (int in = 0; in < 2; in++) {
                    int col = colb + in * 16;
                    s += fmaxf(acc[im][in][q] + fb1[col], 0.f) * fW2[col];
                }
                #pragma unroll
                for (int off = 1; off < 16; off <<= 1) s += __shfl_xor(s, off);
                if ((lane & 15) == 0) atomicAdd(&ypart[rloc + im * 16 + q], s);
            }
        __syncthreads();
        if (tid < 64) atomicAdd(&out[(m0 + tid) * FT_ + step], ypart[tid]);
    }
}

// ---------------- attn2 -> fp32 logits ----------------
__global__ __launch_bounds__(256) void k_a2(const short* __restrict__ s1,
                                            const short* __restrict__ W2b,
                                            const float* __restrict__ ab2,
                                            float* __restrict__ logit) {
    __shared__ short As[64][LDAS];
    __shared__ short Bs[64][LDAS];
    int n0 = blockIdx.x * 64, m0 = blockIdx.y * 64, tid = threadIdx.x;
    f4 acc[2][2] = {};
    gemm64(s1 + m0 * T_, T_, W2b + n0 * T_, T_, T_, As, Bs, tid, acc);
    int lane = tid & 63, w = tid >> 6;
    int wm = (w & 1) * 32, wn = (w >> 1) * 32;
    int colb = n0 + wn + (lane & 15);
    int rowb = m0 + wm + (lane >> 4) * 4;
    #pragma unroll
    for (int im = 0; im < 2; im++)
        #pragma unroll
        for (int in = 0; in < 2; in++) {
            int col = colb + in * 16;
            float bv = ab2[col];
            #pragma unroll
            for (int q = 0; q < 4; q++)
                logit[(rowb + im * 16 + q) * T_ + col] = acc[im][in][q] + bv;
        }
}

// ---------------- softmax*alpha + weighted enc sum; channel-sliced, direct write ----------------
// grid 2048: b = blk>>3, channel slice s = blk&7 (64 channels); thread = 32 ch-pairs x 8 row-groups
__global__ __launch_bounds__(256) void k_ctx(const float* __restrict__ logits,
                                             const float* __restrict__ alpha,
                                             const short* __restrict__ encb,
                                             float* __restrict__ ctx) {
    int b = blockIdx.x >> 3, s = blockIdx.x & 7;
    int tid = threadIdx.x;
    __shared__ float wt[T_];
    __shared__ float red4[4];
    __shared__ float red[8][64];
    const float* lg = logits + b * T_;
    float l0 = lg[tid], l1 = lg[tid + 256];
    float l2 = (tid < 64) ? lg[tid + 512] : -INFINITY;
    float mx = fmaxf(fmaxf(l0, l1), l2);
    for (int off = 32; off; off >>= 1) mx = fmaxf(mx, __shfl_xor(mx, off));
    if ((tid & 63) == 0) red4[tid >> 6] = mx;
    __syncthreads();
    mx = fmaxf(fmaxf(red4[0], red4[1]), fmaxf(red4[2], red4[3]));
    float e0 = expf(l0 - mx), e1 = expf(l1 - mx);
    float e2 = (tid < 64) ? expf(l2 - mx) : 0.f;
    float sme = e0 + e1 + e2;
    for (int off = 32; off; off >>= 1) sme += __shfl_xor(sme, off);
    __syncthreads();
    if ((tid & 63) == 0) red4[tid >> 6] = sme;
    __syncthreads();
    float inv = 1.f / (red4[0] + red4[1] + red4[2] + red4[3]);
    const float* al = alpha + b * 24;
    wt[tid]       = e0 * inv * al[tid / 24];
    wt[tid + 256] = e1 * inv * al[(tid + 256) / 24];
    if (tid < 64) wt[tid + 512] = e2 * inv * al[(tid + 512) / 24];
    __syncthreads();
    int chp = tid & 31, rg = tid >> 5;
    int c0 = s * 64;
    float a0 = 0.f, a1 = 0.f;
    const unsigned* ep = (const unsigned*)(encb + ((size_t)b * T_ + rg * 72) * E_ + c0) + chp;
    const float* wl = wt + rg * 72;
    #pragma unroll 8
    for (int it = 0; it < 72; it++) {
        float wv = wl[it];
        unsigned u = ep[(size_t)it * (E_ / 2)];
        a0 += wv * bf2f((unsigned short)(u & 0xffffu));
        a1 += wv * bf2f((unsigned short)(u >> 16));
    }
    *(float2*)&red[rg][chp * 2] = make_float2(a0, a1);
    __syncthreads();
    if (tid < 64) {
        float sum = 0.f;
        #pragma unroll
        for (int r = 0; r < 8; r++) sum += red[r][tid];
        ctx[b * E_ + c0 + tid] = sum;
    }
}

// ---------------- gates GEMM (gate-permuted cols) + fused LSTM pointwise ----------------
__global__ __launch_bounds__(256) void k_gl(const float* __restrict__ ctxp,
                                            const float* __restrict__ ff, int t,
                                            short* __restrict__ xb,
                                            const short* __restrict__ Wihb,
                                            const short* __restrict__ Whhb,
                                            const float* __restrict__ bcomb,
                                            float* __restrict__ cbuf,
                                            const short* __restrict__ hprev,
                                            short* __restrict__ hnext,
                                            const float* __restrict__ fb2,
                                            float* __restrict__ out) {
    __shared__ union {
        struct { short As[64][LDAS]; short Bs[64][LDAS]; } g;
        float gt[64][68];
    } sm;
    int n0 = blockIdx.x * 64, m0 = blockIdx.y * 64, tid = threadIdx.x;
    int lane = tid & 63, w = tid >> 6;
    int wm = (w & 1) * 32, wn = (w >> 1) * 32;
    int fr = lane & 15, fk = (lane >> 4) * 8;
    int r = tid >> 2, c0 = (tid & 3) * 16, c8 = (tid & 3) * 8;
    f4 acc[2][2] = {};
    // phase 1: inp = [ctx | ff_t], K = 544
    for (int k0 = 0; k0 < KX_; k0 += 64) {
        int rem = KX_ - k0;
        if (rem >= 64) {
            const float* cp = ctxp + (m0 + r) * E_ + k0 + c0;
            short av[16];
            #pragma unroll
            for (int i = 0; i < 16; i++) av[i] = f2bf(cp[i]);
            *(int4*)&sm.g.As[r][c0]     = *(int4*)&av[0];
            *(int4*)&sm.g.As[r][c0 + 8] = *(int4*)&av[8];
            *(int4*)&sm.g.Bs[r][c0]     = *(const int4*)(Wihb + (n0 + r) * KX_ + k0 + c0);
            *(int4*)&sm.g.Bs[r][c0 + 8] = *(const int4*)(Wihb + (n0 + r) * KX_ + k0 + c0 + 8);
        } else {
            const float* fp = ff + ((m0 + r) * FT_ + t) * M_ + (k0 + c8 - E_);
            short av[8];
            #pragma unroll
            for (int i = 0; i < 8; i++) av[i] = f2bf(fp[i]);
            *(int4*)&sm.g.As[r][c8] = *(int4*)&av[0];
            *(int4*)&sm.g.Bs[r][c8] = *(const int4*)(Wihb + (n0 + r) * KX_ + k0 + c8);
        }
        __syncthreads();
        mfma4(sm.g.As, sm.g.Bs, wm, wn, fr, fk, acc);
        if (rem >= 64) mfma4(sm.g.As, sm.g.Bs, wm, wn, fr, fk + 32, acc);
        __syncthreads();
    }
    // phase 2: + h_{t-1}[d] * Whh^T, K = 256
    int d = n0 >> 10;
    gemm64(hprev + d * B_ * H_ + m0 * H_, H_, Whhb + n0 * H_, H_, H_,
           sm.g.As, sm.g.Bs, tid, acc);
    // epilogue: +bias -> LDS, then LSTM pointwise
    int clb = wn + (lane & 15);
    int rlb = wm + (lane >> 4) * 4;
    #pragma unroll
    for (int im = 0; im < 2; im++)
        #pragma unroll
        for (int in = 0; in < 2; in++) {
            int cl = clb + in * 16;
            float bv = bcomb[n0 + cl];
            #pragma unroll
            for (int q = 0; q < 4; q++)
                sm.gt[rlb + im * 16 + q][cl] = acc[im][in][q] + bv;
        }
    __syncthreads();
    int j0 = (n0 >> 2) & 255;
    #pragma unroll
    for (int it = 0; it < 4; it++) {
        int item = tid + it * 256;
        int rl = item >> 4, ql = item & 15;
        float ig = sm.gt[rl][ql * 4 + 0];
        float fg = sm.gt[rl][ql * 4 + 1];
        float gg = sm.gt[rl][ql * 4 + 2];
        float og = sm.gt[rl][ql * 4 + 3];
        int b = m0 + rl, j = j0 + ql;
        int ci = d * 65536 + b * 256 + j;
        float cn = sigm(fg) * cbuf[ci] + sigm(ig) * tanhf(gg);
        float hn = sigm(og) * tanhf(cn);
        cbuf[ci] = cn;
        short hv = f2bf(hn);
        xb[b * KX_ + d * H_ + j] = hv;
        hnext[ci] = hv;
        if (d == 0 && j < M_ && t + 1 < FT_)
            xb[b * KX_ + E_ + j] = f2bf(ff[(b * FT_ + t + 1) * M_ + j]);
        if (n0 == 0 && ql == 0) out[b * FT_ + t] = fb2[0];
    }
}

// ---------------- standalone fc (tail only) ----------------
__global__ __launch_bounds__(256) void k_fc(const short* __restrict__ xb,
                                            const short* __restrict__ fW1b,
                                            const float* __restrict__ fb1,
                                            const float* __restrict__ fW2,
                                            float* __restrict__ out, int step) {
    __shared__ short As[64][LDAS];
    __shared__ short Bs[64][LDAS];
    __shared__ float ypart[64];
    int fb = blockIdx.x, tid = threadIdx.x;
    int m0 = (fb >> 2) * 64, n0 = (fb & 3) * 64;
    f4 acc[2][2] = {};
    gemm64(xb + m0 * KX_, KX_, fW1b + n0 * E_, E_, E_, As, Bs, tid, acc);
    if (tid < 64) ypart[tid] = 0.f;
    __syncthreads();
    int lane = tid & 63, w = tid >> 6;
    int wm = (w & 1) * 32, wn = (w >> 1) * 32;
    int colb = n0 + wn + (lane & 15);
    int rloc = wm + (lane >> 4) * 4;
    #pragma unroll
    for (int im = 0; im < 2; im++)
        #pragma unroll
        for (int q = 0; q < 4; q++) {
            float s = 0.f;
            #pragma unroll
            for (int in = 0; in < 2; in++) {
                int col = colb + in * 16;
                s += fmaxf(acc[im][in][q] + fb1[col], 0.f) * fW2[col];
            }
            #pragma unroll
            for (int off = 1; off < 16; off <<= 1) s += __shfl_xor(s, off);
            if ((lane & 15) == 0) atomicAdd(&ypart[rloc + im * 16 + q], s);
        }
    __syncthreads();
    if (tid < 64) atomicAdd(&out[(m0 + tid) * FT_ + step], ypart[tid]);
}

extern "C" void kernel_launch(void* const* d_in, const int* in_sizes, int n_in,
                              void* d_out, int out_size, void* d_ws, size_t ws_size,
                              hipStream_t stream) {
    (void)in_sizes; (void)n_in; (void)out_size; (void)ws_size;
    const float* enc_f  = (const float*)d_in[0];
    const float* fhist  = (const float*)d_in[1];
    const float* ff     = (const float*)d_in[3];
    const float* hidden = (const float*)d_in[4];
    const float* cell   = (const float*)d_in[5];
    const float* aW1    = (const float*)d_in[6];
    const float* ab1    = (const float*)d_in[7];
    const float* aW2    = (const float*)d_in[8];
    const float* ab2    = (const float*)d_in[9];
    const float* Wih    = (const float*)d_in[10];
    const float* Whh    = (const float*)d_in[11];
    const float* bih    = (const float*)d_in[12];
    const float* bhh    = (const float*)d_in[13];
    const float* fW1    = (const float*)d_in[14];
    const float* fb1    = (const float*)d_in[15];
    const float* fW2    = (const float*)d_in[16];
    const float* fb2    = (const float*)d_in[17];
    float* out = (float*)d_out;

    char* pws = (char*)d_ws;
    auto take = [&](size_t n) { char* r = pws; pws += (n + 255) & ~(size_t)255; return r; };
    float* alpha = (float*)take(B_ * 24 * 4);
    short* xb    = (short*)take(B_ * KX_ * 2);
    short* hA    = (short*)take(2 * B_ * H_ * 2);
    short* hB    = (short*)take(2 * B_ * H_ * 2);
    float* cbuf  = (float*)take(2 * B_ * H_ * 4);
    short* s1    = (short*)take(B_ * T_ * 2);
    float* logit = (float*)take(B_ * T_ * 4);
    float* ctxp  = (float*)take(B_ * E_ * 4);
    float* bcomb = (float*)take(ND_ * 4);
    short* W1b   = (short*)take(T_ * KX_ * 2);
    short* W2b   = (short*)take(T_ * T_ * 2);
    short* Wihb  = (short*)take(ND_ * KX_ * 2);
    short* Whhb  = (short*)take(ND_ * H_ * 2);
    short* fW1b  = (short*)take(H_ * E_ * 2);
    short* encb  = (short*)take((size_t)B_ * T_ * E_ * 2);

    SetupPrm sp;
    sp.enc = enc_f; sp.fhist = fhist; sp.ff = ff; sp.hidden = hidden; sp.cell = cell;
    sp.aW1 = aW1; sp.aW2 = aW2; sp.Wih = Wih; sp.Whh = Whh; sp.bih = bih; sp.bhh = bhh;
    sp.fW1 = fW1;
    sp.W1b = W1b; sp.W2b = W2b; sp.Wihb = Wihb; sp.Whhb = Whhb; sp.fW1b = fW1b;
    sp.encb = encb; sp.xb = xb; sp.hA = hA;
    sp.bcomb = bcomb; sp.alpha = alpha; sp.cbuf = cbuf;

    k_setup<<<2048, 256, 0, stream>>>(sp);

    for (int t = 0; t < FT_; t++) {
        k_a1fc<<<dim3(13, 4), 256, 0, stream>>>(xb, W1b, ab1, s1, fW1b, fb1, fW2, out, t);
        k_a2<<<dim3(9, 4), 256, 0, stream>>>(s1, W2b, ab2, logit);
        k_ctx<<<B_ * 8, 256, 0, stream>>>(logit, alpha, encb, ctxp);
        const short* hprev = (t & 1) ? hB : hA;
        short* hnext       = (t & 1) ? hA : hB;
        k_gl<<<dim3(ND_ / 64, B_ / 64), 256, 0, stream>>>(ctxp, ff, t, xb, Wihb, Whhb,
                                                          bcomb, cbuf, hprev, hnext, fb2, out);
    }
    k_fc<<<16, 256, 0, stream>>>(xb, fW1b, fb1, fW2, out, FT_ - 1);
}